// Round 6
// baseline (468.419 us; speedup 1.0000x reference)
//
#include <hip/hip_runtime.h>
#include <math.h>

#define N_NODES 100000
#define N_EDGES 1600000
#define DIM 64
#define N_LAYERS 6
#define N_COEF 8
#define NSTEP 18              // K=576 / 32
#define NTILE 32              // nodes per kan block-tile
#define KAN_TILES (N_NODES / NTILE)  // 3125
#define KAN_GRID 1024

typedef _Float16 f16x8 __attribute__((ext_vector_type(8)));
typedef float f32x4 __attribute__((ext_vector_type(4)));

__device__ __forceinline__ unsigned f16u(float v) {
    return (unsigned)__builtin_bit_cast(unsigned short, (_Float16)v);
}

// ---------------------------------------------------------------------------
// Weights (f16) in MFMA B-fragment-linear layout. K ordering d-major:
// k = d*9 + r; r==0 -> silu branch (base_w), r=1..8 -> spline basis r-1.
// Lane holds B[k = s*32+(lane>>4)*8+j][o = nt*16+(lane&15)], j=0..7.
// NO intra-fragment permutation (a row-dependent k-permutation on the A side
// cannot be compensated here — one B lane serves all 16 A rows).
// ---------------------------------------------------------------------------
__global__ void build_wcf(const float* __restrict__ bw,
                          const float* __restrict__ sw,
                          const float* __restrict__ ss,
                          uint4* __restrict__ wcf) {
    int idx = blockIdx.x * blockDim.x + threadIdx.x;
    if (idx >= N_LAYERS * NSTEP * 4 * 64) return;
    int lane = idx & 63;
    int nt   = (idx >> 6) & 3;
    int s    = (idx >> 8) % NSTEP;
    int l    = idx / (64 * 4 * NSTEP);
    int o = nt * 16 + (lane & 15);

    unsigned short h[8];
#pragma unroll
    for (int j = 0; j < 8; ++j) {
        int k = s * 32 + ((lane >> 4) << 3) + j;
        int d = k / 9;
        int r = k - d * 9;
        float v;
        if (r == 0) v = bw[(l * DIM + o) * DIM + d];
        else        v = sw[((l * DIM + o) * DIM + d) * N_COEF + (r - 1)] *
                        ss[(l * DIM + o) * DIM + d];
        h[j] = __builtin_bit_cast(unsigned short, (_Float16)v);
    }
    uint4 uh;
    uh.x = (unsigned)h[0] | ((unsigned)h[1] << 16);
    uh.y = (unsigned)h[2] | ((unsigned)h[3] << 16);
    uh.z = (unsigned)h[4] | ((unsigned)h[5] << 16);
    uh.w = (unsigned)h[6] | ((unsigned)h[7] << 16);
    wcf[((l * NSTEP + s) * 4 + nt) * 64 + lane] = uh;
}

// ---------------------------------------------------------------------------
// row_ptr build: one binary search per node, once per call (reused 3x).
// ---------------------------------------------------------------------------
__global__ void build_rowptr(const int* __restrict__ erow, int* __restrict__ rp) {
    int i = blockIdx.x * blockDim.x + threadIdx.x;
    if (i > N_NODES) return;
    if (i == N_NODES) { rp[i] = N_EDGES; return; }
    int a = 0, b = N_EDGES;
    while (a < b) { int m = (a + b) >> 1; if (erow[m] < i) a = m + 1; else b = m; }
    rp[i] = a;
}

// ---------------------------------------------------------------------------
// SpMM, quarter-wide: wave per node; the 4 lane-quarters process 4 edges per
// gather instruction, each lane loading float4 (4 features). Metadata for the
// next 8-edge pair is prefetched (ping-pong). Final: 2 shfl_xor reduces.
// ---------------------------------------------------------------------------
#define META4(C, V, E)                                                  \
    { int e_ = (E) + q; if (e_ < end) { C = ecol[e_]; V = ev[e_]; }     \
      else { C = 0; V = 0.f; } }

__global__ __launch_bounds__(256) void spmm_kernel(const int* __restrict__ rp,
                                                   const int* __restrict__ ecol,
                                                   const float* __restrict__ ev,
                                                   const float* __restrict__ x,
                                                   float* __restrict__ y) {
    int wid = (blockIdx.x * blockDim.x + threadIdx.x) >> 6;
    int lane = threadIdx.x & 63;
    if (wid >= N_NODES) return;
    int q = lane >> 4;        // quarter = which edge of the group
    int c16 = lane & 15;      // 16B chunk within the row
    int e0 = rp[wid], end = rp[wid + 1];

    float4 acc = {0.f, 0.f, 0.f, 0.f};
    int c0 = 0, c1 = 0; float v0 = 0.f, v1 = 0.f;
    if (e0 < end) { META4(c0, v0, e0) META4(c1, v1, e0 + 4) }

    for (int eb = e0; eb < end; eb += 8) {
        int n0 = 0, n1 = 0; float w0 = 0.f, w1 = 0.f;
        if (eb + 8 < end) { META4(n0, w0, eb + 8) META4(n1, w1, eb + 12) }
        float4 g0 = *(const float4*)&x[(size_t)c0 * DIM + c16 * 4];
        float4 g1 = *(const float4*)&x[(size_t)c1 * DIM + c16 * 4];
        acc.x += v0 * g0.x; acc.y += v0 * g0.y; acc.z += v0 * g0.z; acc.w += v0 * g0.w;
        acc.x += v1 * g1.x; acc.y += v1 * g1.y; acc.z += v1 * g1.z; acc.w += v1 * g1.w;
        c0 = n0; v0 = w0; c1 = n1; v1 = w1;
    }

    // reduce across quarters (lanes l, l^16, l^32, l^48)
    acc.x += __shfl_xor(acc.x, 16); acc.y += __shfl_xor(acc.y, 16);
    acc.z += __shfl_xor(acc.z, 16); acc.w += __shfl_xor(acc.w, 16);
    acc.x += __shfl_xor(acc.x, 32); acc.y += __shfl_xor(acc.y, 32);
    acc.z += __shfl_xor(acc.z, 32); acc.w += __shfl_xor(acc.w, 32);

    if (lane < 16) *(float4*)&y[(size_t)wid * DIM + c16 * 4] = acc;
}

// ---------------------------------------------------------------------------
// Spline window: 4 nonzero cubic B-spline bases as f16 pairs, positioned into
// an 8-slot (128-bit) window via 64-bit shifts. Slots kb=0..3 -> lo, 4..7 -> hi.
// ---------------------------------------------------------------------------
__device__ __forceinline__ void spline_window(float xv, unsigned long long& lo,
                                              unsigned long long& hi) {
    float t = xv * 2.5f + 5.5f;        // grid units on extended grid, h=0.4
    float fl = floorf(t);
    float u = t - fl;
    int c = (int)fl;
    bool valid = (t >= 0.f) && (t < 11.f);
    float u2 = u * u, u3 = u2 * u, um = 1.f - u;
    const float k6 = 1.f / 6.f;
    float N0 = um * um * um * k6;
    float N1 = (3.f * u3 - 6.f * u2 + 4.f) * k6;
    float N2 = (-3.f * u3 + 3.f * u2 + 3.f * u + 1.f) * k6;
    float N3 = u3 * k6;
    if (!valid) { N0 = 0.f; N1 = 0.f; N2 = 0.f; N3 = 0.f; }
    unsigned n01 = f16u(N0) | (f16u(N1) << 16);
    unsigned n23 = f16u(N2) | (f16u(N3) << 16);
    unsigned long long big = (unsigned long long)n01 | ((unsigned long long)n23 << 32);
    int qb = c - 3;
    qb = qb < -3 ? -3 : (qb > 7 ? 7 : qb);   // invalid => big==0, clamp keeps shifts legal
    int sh = qb * 16;
    lo = 0; hi = 0;
    if (sh >= 0) {
        if (sh < 64) { lo = big << sh; hi = (big >> 1) >> (63 - sh); }  // N3>=0 => bit63==0
        else         { hi = big << (sh - 64); }
    } else {
        lo = big >> (-sh);
    }
}

// ---------------------------------------------------------------------------
// Fused KANLinear via f16 MFMA (16x16x32), single (hi) weight product.
// Persistent blocks; weights in 72 VGPR; __launch_bounds__(256,4) -> 4
// blocks/CU. LDS: XOR-swizzled row-major [32 nodes][576 f16]; 16B block at
// logical octave koct of node n lives at physical octave koct ^ (n&7)
// (octave-level only — proven correct in R3/R4). Next tile's x prefetched
// into registers during the MFMA phase.
// ---------------------------------------------------------------------------
__global__ __launch_bounds__(256, 4) void kan_mfma(const float* __restrict__ xin,
                                                   const uint4* __restrict__ wl,
                                                   float* __restrict__ out) {
    __shared__ alignas(16) char lds[NTILE * 1152];  // 36864 B

    int tid = threadIdx.x;
    int lane = tid & 63;
    int w = tid >> 6;

    // --- weights once: 18 x f16x8 = 72 VGPR ---
    f16x8 bh[NSTEP];
#pragma unroll
    for (int s = 0; s < NSTEP; ++s)
        bh[s] = __builtin_bit_cast(f16x8, wl[(s * 4 + w) * 64 + lane]);

    int fn = tid >> 3;
    int fq = tid & 7;
    int Xsw = (fn & 7) << 4;
    int lbase = fn * 1152;
    int row = lane & 15, kg = lane >> 4;
    int xr = (row & 7) << 4;
    int rb0 = row * 1152;
    int rb1 = (16 + row) * 1152;
    int o = w * 16 + row;
    int rbase = kg * 4;

    int tile = blockIdx.x;
    float4 xv0 = {0,0,0,0}, xv1 = {0,0,0,0};
    if (tile < KAN_TILES) {
        const float* xr_ = &xin[(size_t)(tile * NTILE + fn) * DIM + fq * 4];
        xv0 = *(const float4*)(xr_);
        xv1 = *(const float4*)(xr_ + 32);
    }

    for (; tile < KAN_TILES; tile += gridDim.x) {
        int node0 = tile * NTILE;

        // ---- feature phase (from registers) ----
#pragma unroll
        for (int i = 0; i < 2; ++i) {
            float4 xv4 = i ? xv1 : xv0;
#pragma unroll
            for (int p = 0; p < 2; ++p) {
                int d = fq * 4 + i * 32 + p * 2;   // even
                float xe = p ? xv4.z : xv4.x;
                float xo = p ? xv4.w : xv4.y;

                float se_f = xe * __builtin_amdgcn_rcpf(1.f + __expf(-xe));
                float so_f = xo * __builtin_amdgcn_rcpf(1.f + __expf(-xo));
                unsigned se = f16u(se_f), so = f16u(so_f);

                unsigned long long loE, hiE, loO, hiO;
                spline_window(xe, loE, hiE);
                spline_window(xo, loO, hiO);

                unsigned wv[9];
                wv[0] = se | ((unsigned)loE << 16);
                wv[1] = (unsigned)(loE >> 16);
                wv[2] = (unsigned)(loE >> 48) | ((unsigned)hiE << 16);
                wv[3] = (unsigned)(hiE >> 16);
                wv[4] = (unsigned)(hiE >> 48) | (so << 16);
                wv[5] = (unsigned)loO;
                wv[6] = (unsigned)(loO >> 32);
                wv[7] = (unsigned)hiO;
                wv[8] = (unsigned)(hiO >> 32);

                int base = lbase + 18 * d;   // d even -> 4B aligned
#pragma unroll
                for (int j = 0; j < 9; ++j)
                    *(unsigned*)(&lds[(base + 4 * j) ^ Xsw]) = wv[j];
            }
        }
        __syncthreads();

        // ---- prefetch next tile's x into registers ----
        int tnext = tile + gridDim.x;
        float4 nx0 = {0,0,0,0}, nx1 = {0,0,0,0};
        if (tnext < KAN_TILES) {
            const float* xr_ = &xin[(size_t)(tnext * NTILE + fn) * DIM + fq * 4];
            nx0 = *(const float4*)(xr_);
            nx1 = *(const float4*)(xr_ + 32);
        }

        // ---- MFMA phase ----
        f32x4 acc0 = {0.f, 0.f, 0.f, 0.f};
        f32x4 acc1 = {0.f, 0.f, 0.f, 0.f};
#pragma unroll
        for (int s = 0; s < NSTEP; ++s) {
            int pofs = ((s * 4 + kg) << 4) ^ xr;
            f16x8 a0 = *(const f16x8*)(&lds[rb0 + pofs]);
            f16x8 a1 = *(const f16x8*)(&lds[rb1 + pofs]);
            acc0 = __builtin_amdgcn_mfma_f32_16x16x32_f16(a0, bh[s], acc0, 0, 0, 0);
            acc1 = __builtin_amdgcn_mfma_f32_16x16x32_f16(a1, bh[s], acc1, 0, 0, 0);
        }

        // ---- store: C layout col=lane&15, row=(lane>>4)*4+r ----
#pragma unroll
        for (int r = 0; r < 4; ++r) {
            out[(size_t)(node0 + rbase + r) * DIM + o]      = acc0[r];
            out[(size_t)(node0 + 16 + rbase + r) * DIM + o] = acc1[r];
        }
        __syncthreads();
        xv0 = nx0; xv1 = nx1;
    }
}

extern "C" void kernel_launch(void* const* d_in, const int* in_sizes, int n_in,
                              void* d_out, int out_size, void* d_ws, size_t ws_size,
                              hipStream_t stream) {
    const float* x     = (const float*)d_in[0];
    const float* eval_ = (const float*)d_in[1];
    const float* bw    = (const float*)d_in[2];
    const float* sw    = (const float*)d_in[3];
    const float* ss    = (const float*)d_in[4];
    const int*   erow  = (const int*)d_in[5];
    const int*   ecol  = (const int*)d_in[6];
    float* out = (float*)d_out;

    // ws layout: [A: 25.6MB][wcf: 442368B][row_ptr: 400004B]
    float* A   = (float*)d_ws;
    uint4* wcf = (uint4*)((char*)d_ws + (size_t)N_NODES * DIM * sizeof(float));
    int*   rp  = (int*)((char*)d_ws + (size_t)N_NODES * DIM * sizeof(float) + 442368);

    const size_t WL = (size_t)NSTEP * 4 * 64;  // uint4 per layer

    build_wcf<<<(N_LAYERS * NSTEP * 4 * 64 + 255) / 256, 256, 0, stream>>>(bw, sw, ss, wcf);
    build_rowptr<<<(N_NODES + 256) / 256, 256, 0, stream>>>(erow, rp);

    const int SPMM_BLOCKS = N_NODES / 4;

    spmm_kernel<<<SPMM_BLOCKS, 256, 0, stream>>>(rp, ecol, eval_, x, out);
    kan_mfma<<<KAN_GRID, 256, 0, stream>>>(out, wcf + 0 * WL, A);
    kan_mfma<<<KAN_GRID, 256, 0, stream>>>(A,   wcf + 1 * WL, out);

    spmm_kernel<<<SPMM_BLOCKS, 256, 0, stream>>>(rp, ecol, eval_, out, A);
    kan_mfma<<<KAN_GRID, 256, 0, stream>>>(A,   wcf + 2 * WL, out);
    kan_mfma<<<KAN_GRID, 256, 0, stream>>>(out, wcf + 3 * WL, A);

    spmm_kernel<<<SPMM_BLOCKS, 256, 0, stream>>>(rp, ecol, eval_, A, out);
    kan_mfma<<<KAN_GRID, 256, 0, stream>>>(out, wcf + 4 * WL, A);
    kan_mfma<<<KAN_GRID, 256, 0, stream>>>(A,   wcf + 5 * WL, out);
}

// Round 7
// 309.114 us; speedup vs baseline: 1.5154x; 1.5154x over previous
//
#include <hip/hip_runtime.h>
#include <math.h>

#define N_NODES 100000
#define N_EDGES 1600000
#define DIM 64
#define N_LAYERS 6
#define N_COEF 8
#define NSTEP 18              // K=576 / 32
#define NTILE 32              // nodes per kan block-tile
#define KAN_TILES (N_NODES / NTILE)  // 3125

typedef _Float16 f16x8 __attribute__((ext_vector_type(8)));
typedef float f32x4 __attribute__((ext_vector_type(4)));

__device__ __forceinline__ unsigned f16u(float v) {
    return (unsigned)__builtin_bit_cast(unsigned short, (_Float16)v);
}

// ---------------------------------------------------------------------------
// Weights (f16) in MFMA B-fragment-linear layout. K ordering d-major:
// k = d*9 + r; r==0 -> silu branch (base_w), r=1..8 -> spline basis r-1.
// Lane holds B[k = s*32+(lane>>4)*8+j][o = nt*16+(lane&15)], j=0..7.
// No intra-fragment permutation (row-dependent A-side k-permutation cannot
// be compensated on the B side — R5 lesson).
// ---------------------------------------------------------------------------
__global__ void build_wcf(const float* __restrict__ bw,
                          const float* __restrict__ sw,
                          const float* __restrict__ ss,
                          uint4* __restrict__ wcf) {
    int idx = blockIdx.x * blockDim.x + threadIdx.x;
    if (idx >= N_LAYERS * NSTEP * 4 * 64) return;
    int lane = idx & 63;
    int nt   = (idx >> 6) & 3;
    int s    = (idx >> 8) % NSTEP;
    int l    = idx / (64 * 4 * NSTEP);
    int o = nt * 16 + (lane & 15);

    unsigned short h[8];
#pragma unroll
    for (int j = 0; j < 8; ++j) {
        int k = s * 32 + ((lane >> 4) << 3) + j;
        int d = k / 9;
        int r = k - d * 9;
        float v;
        if (r == 0) v = bw[(l * DIM + o) * DIM + d];
        else        v = sw[((l * DIM + o) * DIM + d) * N_COEF + (r - 1)] *
                        ss[(l * DIM + o) * DIM + d];
        h[j] = __builtin_bit_cast(unsigned short, (_Float16)v);
    }
    uint4 uh;
    uh.x = (unsigned)h[0] | ((unsigned)h[1] << 16);
    uh.y = (unsigned)h[2] | ((unsigned)h[3] << 16);
    uh.z = (unsigned)h[4] | ((unsigned)h[5] << 16);
    uh.w = (unsigned)h[6] | ((unsigned)h[7] << 16);
    wcf[((l * NSTEP + s) * 4 + nt) * 64 + lane] = uh;
}

// ---------------------------------------------------------------------------
// row_ptr build: one binary search per node, once per call (reused 3x).
// ---------------------------------------------------------------------------
__global__ void build_rowptr(const int* __restrict__ erow, int* __restrict__ rp) {
    int i = blockIdx.x * blockDim.x + threadIdx.x;
    if (i > N_NODES) return;
    if (i == N_NODES) { rp[i] = N_EDGES; return; }
    int a = 0, b = N_EDGES;
    while (a < b) { int m = (a + b) >> 1; if (erow[m] < i) a = m + 1; else b = m; }
    rp[i] = a;
}

// ---------------------------------------------------------------------------
// SpMM, quarter-wide: wave per node; the 4 lane-quarters process 4 edges per
// gather instruction, each lane loading float4 (4 features). Metadata for the
// next 8-edge pair is prefetched (ping-pong). Final: 2 shfl_xor reduces.
// ---------------------------------------------------------------------------
#define META4(C, V, E)                                                  \
    { int e_ = (E) + q; if (e_ < end) { C = ecol[e_]; V = ev[e_]; }     \
      else { C = 0; V = 0.f; } }

__global__ __launch_bounds__(256) void spmm_kernel(const int* __restrict__ rp,
                                                   const int* __restrict__ ecol,
                                                   const float* __restrict__ ev,
                                                   const float* __restrict__ x,
                                                   float* __restrict__ y) {
    int wid = (blockIdx.x * blockDim.x + threadIdx.x) >> 6;
    int lane = threadIdx.x & 63;
    if (wid >= N_NODES) return;
    int q = lane >> 4;        // quarter = which edge of the group
    int c16 = lane & 15;      // 16B chunk within the row
    int e0 = rp[wid], end = rp[wid + 1];

    float4 acc = {0.f, 0.f, 0.f, 0.f};
    int c0 = 0, c1 = 0; float v0 = 0.f, v1 = 0.f;
    if (e0 < end) { META4(c0, v0, e0) META4(c1, v1, e0 + 4) }

    for (int eb = e0; eb < end; eb += 8) {
        int n0 = 0, n1 = 0; float w0 = 0.f, w1 = 0.f;
        if (eb + 8 < end) { META4(n0, w0, eb + 8) META4(n1, w1, eb + 12) }
        float4 g0 = *(const float4*)&x[(size_t)c0 * DIM + c16 * 4];
        float4 g1 = *(const float4*)&x[(size_t)c1 * DIM + c16 * 4];
        acc.x += v0 * g0.x; acc.y += v0 * g0.y; acc.z += v0 * g0.z; acc.w += v0 * g0.w;
        acc.x += v1 * g1.x; acc.y += v1 * g1.y; acc.z += v1 * g1.z; acc.w += v1 * g1.w;
        c0 = n0; v0 = w0; c1 = n1; v1 = w1;
    }

    acc.x += __shfl_xor(acc.x, 16); acc.y += __shfl_xor(acc.y, 16);
    acc.z += __shfl_xor(acc.z, 16); acc.w += __shfl_xor(acc.w, 16);
    acc.x += __shfl_xor(acc.x, 32); acc.y += __shfl_xor(acc.y, 32);
    acc.z += __shfl_xor(acc.z, 32); acc.w += __shfl_xor(acc.w, 32);

    if (lane < 16) *(float4*)&y[(size_t)wid * DIM + c16 * 4] = acc;
}

// ---------------------------------------------------------------------------
// Spline window: 4 nonzero cubic B-spline bases as f16 pairs, positioned into
// an 8-slot (128-bit) window via 64-bit shifts.
// ---------------------------------------------------------------------------
__device__ __forceinline__ void spline_window(float xv, unsigned long long& lo,
                                              unsigned long long& hi) {
    float t = xv * 2.5f + 5.5f;        // grid units on extended grid, h=0.4
    float fl = floorf(t);
    float u = t - fl;
    int c = (int)fl;
    bool valid = (t >= 0.f) && (t < 11.f);
    float u2 = u * u, u3 = u2 * u, um = 1.f - u;
    const float k6 = 1.f / 6.f;
    float N0 = um * um * um * k6;
    float N1 = (3.f * u3 - 6.f * u2 + 4.f) * k6;
    float N2 = (-3.f * u3 + 3.f * u2 + 3.f * u + 1.f) * k6;
    float N3 = u3 * k6;
    if (!valid) { N0 = 0.f; N1 = 0.f; N2 = 0.f; N3 = 0.f; }
    unsigned n01 = f16u(N0) | (f16u(N1) << 16);
    unsigned n23 = f16u(N2) | (f16u(N3) << 16);
    unsigned long long big = (unsigned long long)n01 | ((unsigned long long)n23 << 32);
    int qb = c - 3;
    qb = qb < -3 ? -3 : (qb > 7 ? 7 : qb);   // invalid => big==0, clamp keeps shifts legal
    int sh = qb * 16;
    lo = 0; hi = 0;
    if (sh >= 0) {
        if (sh < 64) { lo = big << sh; hi = (big >> 1) >> (63 - sh); }  // N3>=0 => bit63==0
        else         { hi = big << (sh - 64); }
    } else {
        lo = big >> (-sh);
    }
}

// ---------------------------------------------------------------------------
// Feature phase helper: compute features for an (even,odd) pair of x values
// and write the 9 packed dwords to swizzled LDS.
// ---------------------------------------------------------------------------
__device__ __forceinline__ void feat_pair(char* lds, int lbase, int Xsw, int d,
                                          float xe, float xo) {
    float se_f = xe * __builtin_amdgcn_rcpf(1.f + __expf(-xe));
    float so_f = xo * __builtin_amdgcn_rcpf(1.f + __expf(-xo));
    unsigned se = f16u(se_f), so = f16u(so_f);

    unsigned long long loE, hiE, loO, hiO;
    spline_window(xe, loE, hiE);
    spline_window(xo, loO, hiO);

    unsigned wv[9];
    wv[0] = se | ((unsigned)loE << 16);
    wv[1] = (unsigned)(loE >> 16);
    wv[2] = (unsigned)(loE >> 48) | ((unsigned)hiE << 16);
    wv[3] = (unsigned)(hiE >> 16);
    wv[4] = (unsigned)(hiE >> 48) | (so << 16);
    wv[5] = (unsigned)loO;
    wv[6] = (unsigned)(loO >> 32);
    wv[7] = (unsigned)hiO;
    wv[8] = (unsigned)(hiO >> 32);

    int base = lbase + 18 * d;   // d even -> 4B aligned
#pragma unroll
    for (int j = 0; j < 9; ++j)
        *(unsigned*)(&lds[(base + 4 * j) ^ Xsw]) = wv[j];
}

// ---------------------------------------------------------------------------
// Fused KAN pair (two KANLinear layers). Per 32-node tile:
//   featA(global xin) -> LDS feat; MFMA(wlA) -> c1 (LDS, padded f32);
//   featB(c1) -> LDS feat; MFMA(wlB) -> global out.
// Weights stream from L2 inside the MFMA loops (no persistent registers —
// R6 lesson: launch-bounds-capped VGPR budget spills them to scratch).
// LDS feat: [32 nodes][576 f16], octave XOR swizzle (R3/R4-proven).
// ---------------------------------------------------------------------------
__global__ __launch_bounds__(256) void kan2_mfma(const float* __restrict__ xin,
                                                 const uint4* __restrict__ wlA,
                                                 const uint4* __restrict__ wlB,
                                                 float* __restrict__ out) {
    __shared__ alignas(16) char lds[NTILE * 1152];  // 36864 B
    __shared__ float c1[NTILE][DIM + 1];            // 8320 B, padded

    int tid = threadIdx.x;
    int lane = tid & 63;
    int w = tid >> 6;

    int fn = tid >> 3;
    int fq = tid & 7;
    int Xsw = (fn & 7) << 4;
    int lbase = fn * 1152;
    int row = lane & 15, kg = lane >> 4;
    int xr = (row & 7) << 4;
    int rb0 = row * 1152;
    int rb1 = (16 + row) * 1152;
    int o = w * 16 + row;
    int rbase = kg * 4;

    int node0 = blockIdx.x * NTILE;

    // ================= layer A =================
    {
        const float* xr_ = &xin[(size_t)(node0 + fn) * DIM + fq * 4];
        float4 xv0 = *(const float4*)(xr_);
        float4 xv1 = *(const float4*)(xr_ + 32);
#pragma unroll
        for (int i = 0; i < 2; ++i) {
            float4 xv4 = i ? xv1 : xv0;
            int d0 = fq * 4 + i * 32;
            feat_pair(lds, lbase, Xsw, d0,     xv4.x, xv4.y);
            feat_pair(lds, lbase, Xsw, d0 + 2, xv4.z, xv4.w);
        }
    }
    __syncthreads();

    {
        f32x4 acc0 = {0.f, 0.f, 0.f, 0.f};
        f32x4 acc1 = {0.f, 0.f, 0.f, 0.f};
#pragma unroll
        for (int s = 0; s < NSTEP; ++s) {
            f16x8 bh = __builtin_bit_cast(f16x8, wlA[(s * 4 + w) * 64 + lane]);
            int pofs = ((s * 4 + kg) << 4) ^ xr;
            f16x8 a0 = *(const f16x8*)(&lds[rb0 + pofs]);
            f16x8 a1 = *(const f16x8*)(&lds[rb1 + pofs]);
            acc0 = __builtin_amdgcn_mfma_f32_16x16x32_f16(a0, bh, acc0, 0, 0, 0);
            acc1 = __builtin_amdgcn_mfma_f32_16x16x32_f16(a1, bh, acc1, 0, 0, 0);
        }
#pragma unroll
        for (int r = 0; r < 4; ++r) {
            c1[rbase + r][o]      = acc0[r];
            c1[16 + rbase + r][o] = acc1[r];
        }
    }
    __syncthreads();   // c1 complete; feat reads of layer A complete

    // ================= layer B =================
    {
#pragma unroll
        for (int i = 0; i < 2; ++i) {
            int d0 = fq * 4 + i * 32;
            float a = c1[fn][d0], b = c1[fn][d0 + 1];
            float c = c1[fn][d0 + 2], dd = c1[fn][d0 + 3];
            feat_pair(lds, lbase, Xsw, d0,     a, b);
            feat_pair(lds, lbase, Xsw, d0 + 2, c, dd);
        }
    }
    __syncthreads();

    {
        f32x4 acc0 = {0.f, 0.f, 0.f, 0.f};
        f32x4 acc1 = {0.f, 0.f, 0.f, 0.f};
#pragma unroll
        for (int s = 0; s < NSTEP; ++s) {
            f16x8 bh = __builtin_bit_cast(f16x8, wlB[(s * 4 + w) * 64 + lane]);
            int pofs = ((s * 4 + kg) << 4) ^ xr;
            f16x8 a0 = *(const f16x8*)(&lds[rb0 + pofs]);
            f16x8 a1 = *(const f16x8*)(&lds[rb1 + pofs]);
            acc0 = __builtin_amdgcn_mfma_f32_16x16x32_f16(a0, bh, acc0, 0, 0, 0);
            acc1 = __builtin_amdgcn_mfma_f32_16x16x32_f16(a1, bh, acc1, 0, 0, 0);
        }
#pragma unroll
        for (int r = 0; r < 4; ++r) {
            out[(size_t)(node0 + rbase + r) * DIM + o]      = acc0[r];
            out[(size_t)(node0 + 16 + rbase + r) * DIM + o] = acc1[r];
        }
    }
}

extern "C" void kernel_launch(void* const* d_in, const int* in_sizes, int n_in,
                              void* d_out, int out_size, void* d_ws, size_t ws_size,
                              hipStream_t stream) {
    const float* x     = (const float*)d_in[0];
    const float* eval_ = (const float*)d_in[1];
    const float* bw    = (const float*)d_in[2];
    const float* sw    = (const float*)d_in[3];
    const float* ss    = (const float*)d_in[4];
    const int*   erow  = (const int*)d_in[5];
    const int*   ecol  = (const int*)d_in[6];
    float* out = (float*)d_out;

    // ws layout: [A: 25.6MB][wcf: 442368B][row_ptr: 400004B]
    float* A   = (float*)d_ws;
    uint4* wcf = (uint4*)((char*)d_ws + (size_t)N_NODES * DIM * sizeof(float));
    int*   rp  = (int*)((char*)d_ws + (size_t)N_NODES * DIM * sizeof(float) + 442368);

    const size_t WL = (size_t)NSTEP * 4 * 64;  // uint4 per layer

    build_wcf<<<(N_LAYERS * NSTEP * 4 * 64 + 255) / 256, 256, 0, stream>>>(bw, sw, ss, wcf);
    build_rowptr<<<(N_NODES + 256) / 256, 256, 0, stream>>>(erow, rp);

    const int SPMM_BLOCKS = N_NODES / 4;

    spmm_kernel<<<SPMM_BLOCKS, 256, 0, stream>>>(rp, ecol, eval_, x, out);
    kan2_mfma<<<KAN_TILES, 256, 0, stream>>>(out, wcf + 0 * WL, wcf + 1 * WL, A);

    spmm_kernel<<<SPMM_BLOCKS, 256, 0, stream>>>(rp, ecol, eval_, A, out);
    kan2_mfma<<<KAN_TILES, 256, 0, stream>>>(out, wcf + 2 * WL, wcf + 3 * WL, A);

    spmm_kernel<<<SPMM_BLOCKS, 256, 0, stream>>>(rp, ecol, eval_, A, out);
    kan2_mfma<<<KAN_TILES, 256, 0, stream>>>(out, wcf + 4 * WL, wcf + 5 * WL, out);
}

// Round 8
// 284.238 us; speedup vs baseline: 1.6480x; 1.0875x over previous
//
#include <hip/hip_runtime.h>
#include <math.h>

#define N_NODES 100000
#define N_EDGES 1600000
#define DIM 64
#define N_LAYERS 6
#define N_COEF 8
#define NSTEP 18              // K=576 / 32
#define NTILE 16              // nodes per kan block-tile
#define KAN_BLOCKS (N_NODES / NTILE)  // 6250

typedef _Float16 f16x8 __attribute__((ext_vector_type(8)));
typedef _Float16 f16x4 __attribute__((ext_vector_type(4)));
typedef float f32x4 __attribute__((ext_vector_type(4)));

__device__ __forceinline__ unsigned f16u(float v) {
    return (unsigned)__builtin_bit_cast(unsigned short, (_Float16)v);
}

// ---------------------------------------------------------------------------
// Weights (f16) in MFMA B-fragment-linear layout. K ordering d-major:
// k = d*9 + r; r==0 -> silu (base_w), r>=1 -> spline basis r-1.
// Lane holds B[k = s*32+(lane>>4)*8+j][o = nt*16+(lane&15)], j=0..7.
// ---------------------------------------------------------------------------
__global__ void build_wcf(const float* __restrict__ bw,
                          const float* __restrict__ sw,
                          const float* __restrict__ ss,
                          uint4* __restrict__ wcf) {
    int idx = blockIdx.x * blockDim.x + threadIdx.x;
    if (idx >= N_LAYERS * NSTEP * 4 * 64) return;
    int lane = idx & 63;
    int nt   = (idx >> 6) & 3;
    int s    = (idx >> 8) % NSTEP;
    int l    = idx / (64 * 4 * NSTEP);
    int o = nt * 16 + (lane & 15);

    unsigned short h[8];
#pragma unroll
    for (int j = 0; j < 8; ++j) {
        int k = s * 32 + ((lane >> 4) << 3) + j;
        int d = k / 9;
        int r = k - d * 9;
        float v;
        if (r == 0) v = bw[(l * DIM + o) * DIM + d];
        else        v = sw[((l * DIM + o) * DIM + d) * N_COEF + (r - 1)] *
                        ss[(l * DIM + o) * DIM + d];
        h[j] = __builtin_bit_cast(unsigned short, (_Float16)v);
    }
    uint4 uh;
    uh.x = (unsigned)h[0] | ((unsigned)h[1] << 16);
    uh.y = (unsigned)h[2] | ((unsigned)h[3] << 16);
    uh.z = (unsigned)h[4] | ((unsigned)h[5] << 16);
    uh.w = (unsigned)h[6] | ((unsigned)h[7] << 16);
    wcf[((l * NSTEP + s) * 4 + nt) * 64 + lane] = uh;
}

__global__ void build_rowptr(const int* __restrict__ erow, int* __restrict__ rp) {
    int i = blockIdx.x * blockDim.x + threadIdx.x;
    if (i > N_NODES) return;
    if (i == N_NODES) { rp[i] = N_EDGES; return; }
    int a = 0, b = N_EDGES;
    while (a < b) { int m = (a + b) >> 1; if (erow[m] < i) a = m + 1; else b = m; }
    rp[i] = a;
}

// f32 -> f16 convert (initial x only)
__global__ void conv_f16(const float* __restrict__ in, _Float16* __restrict__ out) {
    int i = blockIdx.x * blockDim.x + threadIdx.x;   // one float4 per thread
    float4 v = *(const float4*)(in + (size_t)i * 4);
    f16x4 h = { (_Float16)v.x, (_Float16)v.y, (_Float16)v.z, (_Float16)v.w };
    *(f16x4*)(out + (size_t)i * 4) = h;
}

// ---------------------------------------------------------------------------
// SpMM, quarter-wide, f16 rows: wave per node; 4 lane-quarters process 4
// edges per gather, each lane loads f16x4 (8B) = 4 features. f32 accumulate,
// f16 out. Metadata ping-pong prefetch.
// ---------------------------------------------------------------------------
#define META4(C, V, E)                                                  \
    { int e_ = (E) + q; if (e_ < end) { C = ecol[e_]; V = ev[e_]; }     \
      else { C = 0; V = 0.f; } }

__global__ __launch_bounds__(256) void spmm_kernel(const int* __restrict__ rp,
                                                   const int* __restrict__ ecol,
                                                   const float* __restrict__ ev,
                                                   const _Float16* __restrict__ x,
                                                   _Float16* __restrict__ y) {
    int wid = (blockIdx.x * blockDim.x + threadIdx.x) >> 6;
    int lane = threadIdx.x & 63;
    if (wid >= N_NODES) return;
    int q = lane >> 4;        // quarter = which edge of the group
    int c16 = lane & 15;      // 8B chunk within the 128B row
    int e0 = rp[wid], end = rp[wid + 1];

    float4 acc = {0.f, 0.f, 0.f, 0.f};
    int c0 = 0, c1 = 0; float v0 = 0.f, v1 = 0.f;
    if (e0 < end) { META4(c0, v0, e0) META4(c1, v1, e0 + 4) }

    for (int eb = e0; eb < end; eb += 8) {
        int n0 = 0, n1 = 0; float w0 = 0.f, w1 = 0.f;
        if (eb + 8 < end) { META4(n0, w0, eb + 8) META4(n1, w1, eb + 12) }
        f16x4 g0 = *(const f16x4*)&x[(size_t)c0 * DIM + c16 * 4];
        f16x4 g1 = *(const f16x4*)&x[(size_t)c1 * DIM + c16 * 4];
        acc.x += v0 * (float)g0[0]; acc.y += v0 * (float)g0[1];
        acc.z += v0 * (float)g0[2]; acc.w += v0 * (float)g0[3];
        acc.x += v1 * (float)g1[0]; acc.y += v1 * (float)g1[1];
        acc.z += v1 * (float)g1[2]; acc.w += v1 * (float)g1[3];
        c0 = n0; v0 = w0; c1 = n1; v1 = w1;
    }

    acc.x += __shfl_xor(acc.x, 16); acc.y += __shfl_xor(acc.y, 16);
    acc.z += __shfl_xor(acc.z, 16); acc.w += __shfl_xor(acc.w, 16);
    acc.x += __shfl_xor(acc.x, 32); acc.y += __shfl_xor(acc.y, 32);
    acc.z += __shfl_xor(acc.z, 32); acc.w += __shfl_xor(acc.w, 32);

    if (lane < 16) {
        f16x4 h = { (_Float16)acc.x, (_Float16)acc.y, (_Float16)acc.z, (_Float16)acc.w };
        *(f16x4*)&y[(size_t)wid * DIM + c16 * 4] = h;
    }
}

// ---------------------------------------------------------------------------
// Spline window: 4 nonzero cubic B-spline bases as f16 pairs, positioned into
// an 8-slot (128-bit) window via 64-bit shifts.
// ---------------------------------------------------------------------------
__device__ __forceinline__ void spline_window(float xv, unsigned long long& lo,
                                              unsigned long long& hi) {
    float t = xv * 2.5f + 5.5f;        // grid units on extended grid, h=0.4
    float fl = floorf(t);
    float u = t - fl;
    int c = (int)fl;
    bool valid = (t >= 0.f) && (t < 11.f);
    float u2 = u * u, u3 = u2 * u, um = 1.f - u;
    const float k6 = 1.f / 6.f;
    float N0 = um * um * um * k6;
    float N1 = (3.f * u3 - 6.f * u2 + 4.f) * k6;
    float N2 = (-3.f * u3 + 3.f * u2 + 3.f * u + 1.f) * k6;
    float N3 = u3 * k6;
    if (!valid) { N0 = 0.f; N1 = 0.f; N2 = 0.f; N3 = 0.f; }
    unsigned n01 = f16u(N0) | (f16u(N1) << 16);
    unsigned n23 = f16u(N2) | (f16u(N3) << 16);
    unsigned long long big = (unsigned long long)n01 | ((unsigned long long)n23 << 32);
    int qb = c - 3;
    qb = qb < -3 ? -3 : (qb > 7 ? 7 : qb);   // invalid => big==0, clamp keeps shifts legal
    int sh = qb * 16;
    lo = 0; hi = 0;
    if (sh >= 0) {
        if (sh < 64) { lo = big << sh; hi = (big >> 1) >> (63 - sh); }  // N3>=0 => bit63==0
        else         { hi = big << (sh - 64); }
    } else {
        lo = big >> (-sh);
    }
}

// Feature pair -> 9 packed dwords into octave-swizzled LDS.
__device__ __forceinline__ void feat_pair(char* lds, int lbase, int Xsw, int d,
                                          float xe, float xo) {
    float se_f = xe * __builtin_amdgcn_rcpf(1.f + __expf(-xe));
    float so_f = xo * __builtin_amdgcn_rcpf(1.f + __expf(-xo));
    unsigned se = f16u(se_f), so = f16u(so_f);

    unsigned long long loE, hiE, loO, hiO;
    spline_window(xe, loE, hiE);
    spline_window(xo, loO, hiO);

    unsigned wv[9];
    wv[0] = se | ((unsigned)loE << 16);
    wv[1] = (unsigned)(loE >> 16);
    wv[2] = (unsigned)(loE >> 48) | ((unsigned)hiE << 16);
    wv[3] = (unsigned)(hiE >> 16);
    wv[4] = (unsigned)(hiE >> 48) | (so << 16);
    wv[5] = (unsigned)loO;
    wv[6] = (unsigned)(loO >> 32);
    wv[7] = (unsigned)hiO;
    wv[8] = (unsigned)(hiO >> 32);

    int base = lbase + 18 * d;   // d even -> 4B aligned
#pragma unroll
    for (int j = 0; j < 9; ++j)
        *(unsigned*)(&lds[(base + 4 * j) ^ Xsw]) = wv[j];
}

// ---------------------------------------------------------------------------
// KANLinear via f16 MFMA (16x16x32). NTILE=16 nodes/block -> feat LDS
// 18.4 KB -> 8 blocks/CU; streamed weights; (256,4) launch bounds keep
// VGPR <= 64 (8 waves/SIMD). f16 in, f16 or f32 out. In-place safe (tile
// fully read into LDS before stores).
// ---------------------------------------------------------------------------
template<int F32OUT>
__global__ __launch_bounds__(256, 4) void kan_mfma(const _Float16* __restrict__ xin,
                                                   const uint4* __restrict__ wl,
                                                   void* __restrict__ outp) {
    __shared__ alignas(16) char lds[NTILE * 1152];  // 18432 B

    int tid = threadIdx.x;
    int lane = tid & 63;
    int w = tid >> 6;
    int node0 = blockIdx.x * NTILE;

    // ---- feature phase: fn = node (0..15), fq = quad of d (0..15) ----
    int fn = tid >> 4;
    int fq = tid & 15;
    int Xsw = (fn & 7) << 4;
    int lbase = fn * 1152;
    {
        f16x4 hv = *(const f16x4*)&xin[(size_t)(node0 + fn) * DIM + fq * 4];
        int d0 = fq * 4;
        feat_pair(lds, lbase, Xsw, d0,     (float)hv[0], (float)hv[1]);
        feat_pair(lds, lbase, Xsw, d0 + 2, (float)hv[2], (float)hv[3]);
    }
    __syncthreads();

    // ---- MFMA phase: wave w = o-tile w ----
    int row = lane & 15, kg = lane >> 4;
    int xr = (row & 7) << 4;
    int rb = row * 1152;

    f32x4 acc = {0.f, 0.f, 0.f, 0.f};
#pragma unroll
    for (int s = 0; s < NSTEP; ++s) {
        f16x8 bh = __builtin_bit_cast(f16x8, wl[(s * 4 + w) * 64 + lane]);
        int pofs = ((s * 4 + kg) << 4) ^ xr;
        f16x8 a = *(const f16x8*)(&lds[rb + pofs]);
        acc = __builtin_amdgcn_mfma_f32_16x16x32_f16(a, bh, acc, 0, 0, 0);
    }

    // ---- store: C layout col=lane&15 (o), row=(lane>>4)*4+r (node) ----
    int o = w * 16 + row;
    int rbase = kg * 4;
    if (F32OUT) {
        float* out = (float*)outp;
#pragma unroll
        for (int r = 0; r < 4; ++r)
            out[(size_t)(node0 + rbase + r) * DIM + o] = acc[r];
    } else {
        _Float16* out = (_Float16*)outp;
#pragma unroll
        for (int r = 0; r < 4; ++r)
            out[(size_t)(node0 + rbase + r) * DIM + o] = (_Float16)acc[r];
    }
}

extern "C" void kernel_launch(void* const* d_in, const int* in_sizes, int n_in,
                              void* d_out, int out_size, void* d_ws, size_t ws_size,
                              hipStream_t stream) {
    const float* x     = (const float*)d_in[0];
    const float* eval_ = (const float*)d_in[1];
    const float* bw    = (const float*)d_in[2];
    const float* sw    = (const float*)d_in[3];
    const float* ss    = (const float*)d_in[4];
    const int*   erow  = (const int*)d_in[5];
    const int*   ecol  = (const int*)d_in[6];
    float* out = (float*)d_out;

    // ws layout: [H0: 12.8MB f16][H1: 12.8MB f16][wcf: 442368B][rp: 400004B]
    const size_t HB = (size_t)N_NODES * DIM * sizeof(_Float16);
    _Float16* H0 = (_Float16*)d_ws;
    _Float16* H1 = (_Float16*)((char*)d_ws + HB);
    uint4* wcf = (uint4*)((char*)d_ws + 2 * HB);
    int*   rp  = (int*)((char*)d_ws + 2 * HB + 442368);

    const size_t WL = (size_t)NSTEP * 4 * 64;  // uint4 per layer

    build_wcf<<<(N_LAYERS * NSTEP * 4 * 64 + 255) / 256, 256, 0, stream>>>(bw, sw, ss, wcf);
    build_rowptr<<<(N_NODES + 256) / 256, 256, 0, stream>>>(erow, rp);
    conv_f16<<<(N_NODES * DIM / 4 + 255) / 256, 256, 0, stream>>>(x, H0);

    const int SPMM_BLOCKS = N_NODES / 4;

    spmm_kernel<<<SPMM_BLOCKS, 256, 0, stream>>>(rp, ecol, eval_, H0, H1);
    kan_mfma<0><<<KAN_BLOCKS, 256, 0, stream>>>(H1, wcf + 0 * WL, H1);  // in place
    kan_mfma<0><<<KAN_BLOCKS, 256, 0, stream>>>(H1, wcf + 1 * WL, H0);

    spmm_kernel<<<SPMM_BLOCKS, 256, 0, stream>>>(rp, ecol, eval_, H0, H1);
    kan_mfma<0><<<KAN_BLOCKS, 256, 0, stream>>>(H1, wcf + 2 * WL, H1);  // in place
    kan_mfma<0><<<KAN_BLOCKS, 256, 0, stream>>>(H1, wcf + 3 * WL, H0);

    spmm_kernel<<<SPMM_BLOCKS, 256, 0, stream>>>(rp, ecol, eval_, H0, H1);
    kan_mfma<0><<<KAN_BLOCKS, 256, 0, stream>>>(H1, wcf + 4 * WL, H1);  // in place
    kan_mfma<1><<<KAN_BLOCKS, 256, 0, stream>>>(H1, wcf + 5 * WL, out);
}

// Round 9
// 272.388 us; speedup vs baseline: 1.7197x; 1.0435x over previous
//
#include <hip/hip_runtime.h>
#include <math.h>

#define N_NODES 100000
#define N_EDGES 1600000
#define DIM 64
#define N_LAYERS 6
#define N_COEF 8
#define NSTEP 18              // K=576 / 32
#define NTILE 32              // nodes per kan block-tile
#define KAN_BLOCKS (N_NODES / NTILE)  // 3125

typedef _Float16 f16x8 __attribute__((ext_vector_type(8)));
typedef _Float16 f16x4 __attribute__((ext_vector_type(4)));
typedef float f32x4 __attribute__((ext_vector_type(4)));

__device__ __forceinline__ unsigned f16u(float v) {
    return (unsigned)__builtin_bit_cast(unsigned short, (_Float16)v);
}

// ---------------------------------------------------------------------------
// Weights (f16) in MFMA B-fragment-linear layout. K ordering d-major:
// k = d*9 + r; r==0 -> silu (base_w), r>=1 -> spline basis r-1.
// Lane holds B[k = s*32+(lane>>4)*8+j][o = nt*16+(lane&15)], j=0..7.
// ---------------------------------------------------------------------------
__global__ void build_wcf(const float* __restrict__ bw,
                          const float* __restrict__ sw,
                          const float* __restrict__ ss,
                          uint4* __restrict__ wcf) {
    int idx = blockIdx.x * blockDim.x + threadIdx.x;
    if (idx >= N_LAYERS * NSTEP * 4 * 64) return;
    int lane = idx & 63;
    int nt   = (idx >> 6) & 3;
    int s    = (idx >> 8) % NSTEP;
    int l    = idx / (64 * 4 * NSTEP);
    int o = nt * 16 + (lane & 15);

    unsigned short h[8];
#pragma unroll
    for (int j = 0; j < 8; ++j) {
        int k = s * 32 + ((lane >> 4) << 3) + j;
        int d = k / 9;
        int r = k - d * 9;
        float v;
        if (r == 0) v = bw[(l * DIM + o) * DIM + d];
        else        v = sw[((l * DIM + o) * DIM + d) * N_COEF + (r - 1)] *
                        ss[(l * DIM + o) * DIM + d];
        h[j] = __builtin_bit_cast(unsigned short, (_Float16)v);
    }
    uint4 uh;
    uh.x = (unsigned)h[0] | ((unsigned)h[1] << 16);
    uh.y = (unsigned)h[2] | ((unsigned)h[3] << 16);
    uh.z = (unsigned)h[4] | ((unsigned)h[5] << 16);
    uh.w = (unsigned)h[6] | ((unsigned)h[7] << 16);
    wcf[((l * NSTEP + s) * 4 + nt) * 64 + lane] = uh;
}

__global__ void build_rowptr(const int* __restrict__ erow, int* __restrict__ rp) {
    int i = blockIdx.x * blockDim.x + threadIdx.x;
    if (i > N_NODES) return;
    if (i == N_NODES) { rp[i] = N_EDGES; return; }
    int a = 0, b = N_EDGES;
    while (a < b) { int m = (a + b) >> 1; if (erow[m] < i) a = m + 1; else b = m; }
    rp[i] = a;
}

// f32 -> f16 convert (initial x only)
__global__ void conv_f16(const float* __restrict__ in, _Float16* __restrict__ out) {
    int i = blockIdx.x * blockDim.x + threadIdx.x;   // one float4 per thread
    float4 v = *(const float4*)(in + (size_t)i * 4);
    f16x4 h = { (_Float16)v.x, (_Float16)v.y, (_Float16)v.z, (_Float16)v.w };
    *(f16x4*)(out + (size_t)i * 4) = h;
}

// ---------------------------------------------------------------------------
// SpMM, quarter-wide, f16 rows, 16-edge batches (4 gathers in flight).
// Wave per node; 4 lane-quarters process 4 edges per gather round, each lane
// loads f16x4 (8B). Metadata ping-pong prefetch. f32 accumulate, f16 out.
// ---------------------------------------------------------------------------
#define META16(C, V, BASE)                                              \
    _Pragma("unroll")                                                   \
    for (int i_ = 0; i_ < 4; ++i_) {                                    \
        int e_ = (BASE) + 4 * i_ + q;                                   \
        if (e_ < end) { C[i_] = ecol[e_]; V[i_] = ev[e_]; }             \
        else          { C[i_] = 0;        V[i_] = 0.f; }                \
    }

__global__ __launch_bounds__(256) void spmm_kernel(const int* __restrict__ rp,
                                                   const int* __restrict__ ecol,
                                                   const float* __restrict__ ev,
                                                   const _Float16* __restrict__ x,
                                                   _Float16* __restrict__ y) {
    int wid = (blockIdx.x * blockDim.x + threadIdx.x) >> 6;
    int lane = threadIdx.x & 63;
    if (wid >= N_NODES) return;
    int q = lane >> 4;        // quarter = which edge of the gather round
    int c16 = lane & 15;      // 8B chunk within the 128B row
    int e0 = rp[wid], end = rp[wid + 1];

    float4 acc = {0.f, 0.f, 0.f, 0.f};
    int ca[4]; float va[4];
    int cb[4]; float vb[4];
    META16(ca, va, e0)

    for (int eb = e0; eb < end; eb += 16) {
        META16(cb, vb, eb + 16)
        f16x4 g0 = *(const f16x4*)&x[(size_t)ca[0] * DIM + c16 * 4];
        f16x4 g1 = *(const f16x4*)&x[(size_t)ca[1] * DIM + c16 * 4];
        f16x4 g2 = *(const f16x4*)&x[(size_t)ca[2] * DIM + c16 * 4];
        f16x4 g3 = *(const f16x4*)&x[(size_t)ca[3] * DIM + c16 * 4];
        acc.x += va[0] * (float)g0[0]; acc.y += va[0] * (float)g0[1];
        acc.z += va[0] * (float)g0[2]; acc.w += va[0] * (float)g0[3];
        acc.x += va[1] * (float)g1[0]; acc.y += va[1] * (float)g1[1];
        acc.z += va[1] * (float)g1[2]; acc.w += va[1] * (float)g1[3];
        acc.x += va[2] * (float)g2[0]; acc.y += va[2] * (float)g2[1];
        acc.z += va[2] * (float)g2[2]; acc.w += va[2] * (float)g2[3];
        acc.x += va[3] * (float)g3[0]; acc.y += va[3] * (float)g3[1];
        acc.z += va[3] * (float)g3[2]; acc.w += va[3] * (float)g3[3];
#pragma unroll
        for (int i_ = 0; i_ < 4; ++i_) { ca[i_] = cb[i_]; va[i_] = vb[i_]; }
    }

    acc.x += __shfl_xor(acc.x, 16); acc.y += __shfl_xor(acc.y, 16);
    acc.z += __shfl_xor(acc.z, 16); acc.w += __shfl_xor(acc.w, 16);
    acc.x += __shfl_xor(acc.x, 32); acc.y += __shfl_xor(acc.y, 32);
    acc.z += __shfl_xor(acc.z, 32); acc.w += __shfl_xor(acc.w, 32);

    if (lane < 16) {
        f16x4 h = { (_Float16)acc.x, (_Float16)acc.y, (_Float16)acc.z, (_Float16)acc.w };
        *(f16x4*)&y[(size_t)wid * DIM + c16 * 4] = h;
    }
}

// ---------------------------------------------------------------------------
// Spline window: 4 nonzero cubic B-spline bases as f16 pairs, positioned into
// an 8-slot (128-bit) window via 64-bit shifts.
// ---------------------------------------------------------------------------
__device__ __forceinline__ void spline_window(float xv, unsigned long long& lo,
                                              unsigned long long& hi) {
    float t = xv * 2.5f + 5.5f;        // grid units on extended grid, h=0.4
    float fl = floorf(t);
    float u = t - fl;
    int c = (int)fl;
    bool valid = (t >= 0.f) && (t < 11.f);
    float u2 = u * u, u3 = u2 * u, um = 1.f - u;
    const float k6 = 1.f / 6.f;
    float N0 = um * um * um * k6;
    float N1 = (3.f * u3 - 6.f * u2 + 4.f) * k6;
    float N2 = (-3.f * u3 + 3.f * u2 + 3.f * u + 1.f) * k6;
    float N3 = u3 * k6;
    if (!valid) { N0 = 0.f; N1 = 0.f; N2 = 0.f; N3 = 0.f; }
    unsigned n01 = f16u(N0) | (f16u(N1) << 16);
    unsigned n23 = f16u(N2) | (f16u(N3) << 16);
    unsigned long long big = (unsigned long long)n01 | ((unsigned long long)n23 << 32);
    int qb = c - 3;
    qb = qb < -3 ? -3 : (qb > 7 ? 7 : qb);   // invalid => big==0, clamp keeps shifts legal
    int sh = qb * 16;
    lo = 0; hi = 0;
    if (sh >= 0) {
        if (sh < 64) { lo = big << sh; hi = (big >> 1) >> (63 - sh); }  // N3>=0 => bit63==0
        else         { hi = big << (sh - 64); }
    } else {
        lo = big >> (-sh);
    }
}

// Feature pair -> 9 packed dwords into octave-swizzled LDS.
__device__ __forceinline__ void feat_pair(char* lds, int lbase, int Xsw, int d,
                                          float xe, float xo) {
    float se_f = xe * __builtin_amdgcn_rcpf(1.f + __expf(-xe));
    float so_f = xo * __builtin_amdgcn_rcpf(1.f + __expf(-xo));
    unsigned se = f16u(se_f), so = f16u(so_f);

    unsigned long long loE, hiE, loO, hiO;
    spline_window(xe, loE, hiE);
    spline_window(xo, loO, hiO);

    unsigned wv[9];
    wv[0] = se | ((unsigned)loE << 16);
    wv[1] = (unsigned)(loE >> 16);
    wv[2] = (unsigned)(loE >> 48) | ((unsigned)hiE << 16);
    wv[3] = (unsigned)(hiE >> 16);
    wv[4] = (unsigned)(hiE >> 48) | (so << 16);
    wv[5] = (unsigned)loO;
    wv[6] = (unsigned)(loO >> 32);
    wv[7] = (unsigned)hiO;
    wv[8] = (unsigned)(hiO >> 32);

    int base = lbase + 18 * d;   // d even -> 4B aligned
#pragma unroll
    for (int j = 0; j < 9; ++j)
        *(unsigned*)(&lds[(base + 4 * j) ^ Xsw]) = wv[j];
}

// ---------------------------------------------------------------------------
// KANLinear via f16 MFMA (16x16x32). NTILE=32 nodes/block: each weight
// fragment read from L2 serves TWO m-tiles (halves L2 weight traffic vs
// NTILE=16 — the kan floor per R8 model). LDS feat 36.9 KB -> 4 blocks/CU.
// Default launch bounds (R6 lesson: (256,4) caps VGPR at 64 and spills).
// f16 in, f16 or f32 out. In-place safe.
// ---------------------------------------------------------------------------
template<int F32OUT>
__global__ __launch_bounds__(256) void kan_mfma(const _Float16* __restrict__ xin,
                                                const uint4* __restrict__ wl,
                                                void* __restrict__ outp) {
    __shared__ alignas(16) char lds[NTILE * 1152];  // 36864 B

    int tid = threadIdx.x;
    int lane = tid & 63;
    int w = tid >> 6;
    int node0 = blockIdx.x * NTILE;

    // ---- feature phase: fn = node (0..31), fq = oct of d (0..7) ----
    int fn = tid >> 3;
    int fq = tid & 7;
    int Xsw = (fn & 7) << 4;
    int lbase = fn * 1152;
    {
        const _Float16* xr_ = &xin[(size_t)(node0 + fn) * DIM + fq * 4];
        f16x4 h0 = *(const f16x4*)(xr_);
        f16x4 h1 = *(const f16x4*)(xr_ + 32);
        int d0 = fq * 4;
        feat_pair(lds, lbase, Xsw, d0,          (float)h0[0], (float)h0[1]);
        feat_pair(lds, lbase, Xsw, d0 + 2,      (float)h0[2], (float)h0[3]);
        feat_pair(lds, lbase, Xsw, d0 + 32,     (float)h1[0], (float)h1[1]);
        feat_pair(lds, lbase, Xsw, d0 + 32 + 2, (float)h1[2], (float)h1[3]);
    }
    __syncthreads();

    // ---- MFMA phase: wave w = o-tile w, two m-tiles ----
    int row = lane & 15, kg = lane >> 4;
    int xr = (row & 7) << 4;
    int rb0 = row * 1152;
    int rb1 = (16 + row) * 1152;

    f32x4 acc0 = {0.f, 0.f, 0.f, 0.f};
    f32x4 acc1 = {0.f, 0.f, 0.f, 0.f};
#pragma unroll
    for (int s = 0; s < NSTEP; ++s) {
        f16x8 bh = __builtin_bit_cast(f16x8, wl[(s * 4 + w) * 64 + lane]);
        int pofs = ((s * 4 + kg) << 4) ^ xr;
        f16x8 a0 = *(const f16x8*)(&lds[rb0 + pofs]);
        f16x8 a1 = *(const f16x8*)(&lds[rb1 + pofs]);
        acc0 = __builtin_amdgcn_mfma_f32_16x16x32_f16(a0, bh, acc0, 0, 0, 0);
        acc1 = __builtin_amdgcn_mfma_f32_16x16x32_f16(a1, bh, acc1, 0, 0, 0);
    }

    // ---- store: C layout col=lane&15 (o), row=(lane>>4)*4+r (node) ----
    int o = w * 16 + row;
    int rbase = kg * 4;
    if (F32OUT) {
        float* out = (float*)outp;
#pragma unroll
        for (int r = 0; r < 4; ++r) {
            out[(size_t)(node0 + rbase + r) * DIM + o]      = acc0[r];
            out[(size_t)(node0 + 16 + rbase + r) * DIM + o] = acc1[r];
        }
    } else {
        _Float16* out = (_Float16*)outp;
#pragma unroll
        for (int r = 0; r < 4; ++r) {
            out[(size_t)(node0 + rbase + r) * DIM + o]      = (_Float16)acc0[r];
            out[(size_t)(node0 + 16 + rbase + r) * DIM + o] = (_Float16)acc1[r];
        }
    }
}

extern "C" void kernel_launch(void* const* d_in, const int* in_sizes, int n_in,
                              void* d_out, int out_size, void* d_ws, size_t ws_size,
                              hipStream_t stream) {
    const float* x     = (const float*)d_in[0];
    const float* eval_ = (const float*)d_in[1];
    const float* bw    = (const float*)d_in[2];
    const float* sw    = (const float*)d_in[3];
    const float* ss    = (const float*)d_in[4];
    const int*   erow  = (const int*)d_in[5];
    const int*   ecol  = (const int*)d_in[6];
    float* out = (float*)d_out;

    // ws layout: [H0: 12.8MB f16][H1: 12.8MB f16][wcf: 442368B][rp: 400004B]
    const size_t HB = (size_t)N_NODES * DIM * sizeof(_Float16);
    _Float16* H0 = (_Float16*)d_ws;
    _Float16* H1 = (_Float16*)((char*)d_ws + HB);
    uint4* wcf = (uint4*)((char*)d_ws + 2 * HB);
    int*   rp  = (int*)((char*)d_ws + 2 * HB + 442368);

    const size_t WL = (size_t)NSTEP * 4 * 64;  // uint4 per layer

    build_wcf<<<(N_LAYERS * NSTEP * 4 * 64 + 255) / 256, 256, 0, stream>>>(bw, sw, ss, wcf);
    build_rowptr<<<(N_NODES + 256) / 256, 256, 0, stream>>>(erow, rp);
    conv_f16<<<(N_NODES * DIM / 4 + 255) / 256, 256, 0, stream>>>(x, H0);

    const int SPMM_BLOCKS = N_NODES / 4;

    spmm_kernel<<<SPMM_BLOCKS, 256, 0, stream>>>(rp, ecol, eval_, H0, H1);
    kan_mfma<0><<<KAN_BLOCKS, 256, 0, stream>>>(H1, wcf + 0 * WL, H1);  // in place
    kan_mfma<0><<<KAN_BLOCKS, 256, 0, stream>>>(H1, wcf + 1 * WL, H0);

    spmm_kernel<<<SPMM_BLOCKS, 256, 0, stream>>>(rp, ecol, eval_, H0, H1);
    kan_mfma<0><<<KAN_BLOCKS, 256, 0, stream>>>(H1, wcf + 2 * WL, H1);  // in place
    kan_mfma<0><<<KAN_BLOCKS, 256, 0, stream>>>(H1, wcf + 3 * WL, H0);

    spmm_kernel<<<SPMM_BLOCKS, 256, 0, stream>>>(rp, ecol, eval_, H0, H1);
    kan_mfma<0><<<KAN_BLOCKS, 256, 0, stream>>>(H1, wcf + 4 * WL, H1);  // in place
    kan_mfma<1><<<KAN_BLOCKS, 256, 0, stream>>>(H1, wcf + 5 * WL, out);
}